// Round 1
// baseline (113.903 us; speedup 1.0000x reference)
//
#include <hip/hip_runtime.h>
#include <hip/hip_bf16.h>
#include <math.h>

// MultiHeadAttentionQuantum, B=2048 S=1 E=1024 H=128 DK=NW=8
// All inputs/outputs float32.
//
// Algebra: S==1 -> attention out == v = x @ Wv^T (wq,wk dead).
// RX compose additively; CNOTs are XOR basis permutations ->
//   t_j = cos(v_j + rx_j);  qout[0]=t1*...*t7;  qout[w>=1]=t0*...*tw
// out = qout @ Wc^T + bc
//
// R9: timed region = 2x 256MiB harness poison fills (~87us, fixed) + our
// ~26us of kernels. GEMMs are LDS-read-pipe bound: 16x32 wave tile = 1.5
// ds_read_b128 per MFMA. Fix: 32x32 wave tile via split-K wave layout
// (8 waves = 2m x 2n x 2k), ratio 1.0, SAME 16 waves/CU occupancy.
// Cross-k LDS reduction (16KB) once per block in the epilogue.

#define BB 2048
#define EN 1024

typedef short s16x8 __attribute__((ext_vector_type(8)));
typedef float f32x4 __attribute__((ext_vector_type(4)));

union Frag { s16x8 v; __hip_bfloat16 h[8]; };

__device__ inline s16x8 cvt_frag(f32x4 lo, f32x4 hi) {
    Frag u;
    #pragma unroll
    for (int j = 0; j < 4; ++j) {
        u.h[j]     = __float2bfloat16(lo[j]);
        u.h[4 + j] = __float2bfloat16(hi[j]);
    }
    return u.v;
}

// async 16B/lane global -> LDS (lds base wave-uniform; HW adds lane*16)
__device__ inline void gll16(const __hip_bfloat16* g, __hip_bfloat16* l) {
    __builtin_amdgcn_global_load_lds(
        (const __attribute__((address_space(1))) void*)g,
        (__attribute__((address_space(3))) void*)l,
        16, 0, 0);
}

// Convert x (262144 groups), wv, wc (131072 groups each) -> bf16.
__global__ __launch_bounds__(256) void cvt3_kernel(
        const float* __restrict__ x, const float* __restrict__ wv,
        const float* __restrict__ wc,
        __hip_bfloat16* __restrict__ xb, __hip_bfloat16* __restrict__ wvb,
        __hip_bfloat16* __restrict__ wcb)
{
    const int g = blockIdx.x * 256 + threadIdx.x;   // 0 .. 524287
    const int NX = (BB * EN) / 8;                   // 262144
    const int NG = (EN * EN) / 8;                   // 131072
    const float* s; __hip_bfloat16* d; size_t off;
    if (g < NX)           { s = x;  d = xb;  off = (size_t)g * 8; }
    else if (g < NX + NG) { s = wv; d = wvb; off = (size_t)(g - NX) * 8; }
    else                  { s = wc; d = wcb; off = (size_t)(g - NX - NG) * 8; }
    f32x4 lo = *(const f32x4*)(s + off);
    f32x4 hi = *(const f32x4*)(s + off + 4);
    *(s16x8*)(d + off) = cvt_frag(lo, hi);
}

// GEMM: C[m,n] = sum_k A[m,k]*W[n,k]; A 2048xEN bf16, W ENxEN bf16.
// Tile 64x64, 512 thr = 8 waves arranged 2m x 2n x 2k: wave tile 32x32,
// wave wk owns k-subtile kt==wk of every BK=64 step (4 ds_read_b128 +
// 4 MFMA per step per wave). Double-buffered frag-ordered LDS (32 KB):
// frag-tile = 512 elems (16 rows x 32 k), lane l's fragment at
// tile_base + l*8 elems. A tile (mt,kt) at (mt*2+kt)*512; B tile (nt,kt)
// at 4096+(nt*2+kt)*512.
// Epilogue: wk=1 waves dump partial acc to LDS (red, 16 KB @ byte 17408),
// wk=0 waves add.
// EPI 0: quantum epilogue (in-LDS 64x68 transpose) -> bf16 V.
// EPI 1: +bias -> f32 out.
template <int EPI>
__global__ __launch_bounds__(512, 4) void gemm_kernel(
        const __hip_bfloat16* __restrict__ A,
        const __hip_bfloat16* __restrict__ W,
        const float* __restrict__ bias, const float* __restrict__ rx,
        void* __restrict__ Cv)
{
    __shared__ __align__(16) unsigned char smem[33792];
    __hip_bfloat16* lds = (__hip_bfloat16*)smem;

    const int tid  = threadIdx.x;
    const int wave = tid >> 6, lane = tid & 63;
    const int l15 = lane & 15, lq = lane >> 4;
    const int m0 = blockIdx.x * 64, n0 = blockIdx.y * 64;
    const int wk  = wave >> 2;          // 0..1: owned 32-k subtile per step
    const int wmn = wave & 3;
    const int wm  = wmn >> 1;           // 0..1  (32-row wave tile)
    const int wn  = wmn & 1;            // 0..1  (32-col wave tile)

    // staging: wave stages 2 of 16 frag-tiles: t = wave*2 + i
    const __hip_bfloat16* gsrc[2];
    int ldst[2];
    #pragma unroll
    for (int i = 0; i < 2; ++i) {
        const int t = wave * 2 + i;
        int row, lofs;
        const __hip_bfloat16* base;
        if (t < 8) { const int mt = t >> 1; row = m0 + mt * 16 + l15; base = A; lofs = t * 512; }
        else       { const int u = t - 8;   row = n0 + (u >> 1) * 16 + l15; base = W; lofs = 4096 + u * 512; }
        gsrc[i] = base + (size_t)row * EN + (t & 1) * 32 + lq * 8;
        ldst[i] = lofs;
    }

    f32x4 acc[2][2] = {};

    #pragma unroll
    for (int i = 0; i < 2; ++i) gll16(gsrc[i], &lds[ldst[i]]);
    __syncthreads();

    int p = 0;
    for (int k0 = 64; k0 <= EN; k0 += 64) {
        if (k0 < EN) {
            const int q = p ^ 1;
            #pragma unroll
            for (int i = 0; i < 2; ++i) gll16(gsrc[i] + k0, &lds[q * 8192 + ldst[i]]);
        }
        const __hip_bfloat16* Ab = &lds[p * 8192];
        const __hip_bfloat16* Bb = Ab + 4096;
        s16x8 a[2], b[2];
        #pragma unroll
        for (int mi = 0; mi < 2; ++mi)
            a[mi] = *(const s16x8*)&Ab[((wm * 2 + mi) * 2 + wk) * 512 + lane * 8];
        #pragma unroll
        for (int nj = 0; nj < 2; ++nj)
            b[nj] = *(const s16x8*)&Bb[((wn * 2 + nj) * 2 + wk) * 512 + lane * 8];
        #pragma unroll
        for (int mi = 0; mi < 2; ++mi) {
            #pragma unroll
            for (int nj = 0; nj < 2; ++nj)
                acc[mi][nj] = __builtin_amdgcn_mfma_f32_16x16x32_bf16(
                    a[mi], b[nj], acc[mi][nj], 0, 0, 0);
        }
        __syncthreads();
        p ^= 1;
    }

    // cross-k reduction: wk=1 partials -> LDS, wk=0 waves add.
    // red: 16 tiles of 256 f32 (lane*4 contiguous), bytes 17408..33791.
    float* red = (float*)(smem + 17408);
    if (wk == 1) {
        #pragma unroll
        for (int mi = 0; mi < 2; ++mi) {
            #pragma unroll
            for (int nj = 0; nj < 2; ++nj)
                *(f32x4*)&red[((wmn * 2 + mi) * 2 + nj) * 256 + lane * 4] = acc[mi][nj];
        }
    }
    __syncthreads();

    if (EPI == 0) {
        // quantum epilogue: summed acc -> LDS f32 64x68 -> cos/products -> bf16 V
        float* sb = (float*)smem;                       // 17408 B, dbuf is dead
        if (wk == 0) {
            #pragma unroll
            for (int mi = 0; mi < 2; ++mi) {
                #pragma unroll
                for (int nj = 0; nj < 2; ++nj) {
                    f32x4 o = *(const f32x4*)&red[((wmn * 2 + mi) * 2 + nj) * 256 + lane * 4];
                    const int col = wn * 32 + nj * 16 + l15;
                    #pragma unroll
                    for (int r = 0; r < 4; ++r)
                        sb[(wm * 32 + mi * 16 + lq * 4 + r) * 68 + col] = acc[mi][nj][r] + o[r];
                }
            }
        }
        __syncthreads();
        const int row = tid >> 3, g = tid & 7;          // 64 rows x 8 groups
        const float* pv = &sb[row * 68 + g * 8];
        float t[8];
        #pragma unroll
        for (int j = 0; j < 8; ++j) t[j] = __cosf(pv[j] + rx[j]);
        Frag o;
        float suf = t[1];
        #pragma unroll
        for (int j = 2; j < 8; ++j) suf *= t[j];
        o.h[0] = __float2bfloat16(suf);
        float pr = t[0];
        #pragma unroll
        for (int j = 1; j < 8; ++j) { pr *= t[j]; o.h[j] = __float2bfloat16(pr); }
        __hip_bfloat16* V = (__hip_bfloat16*)Cv;
        *(s16x8*)(V + (size_t)(m0 + row) * EN + n0 + g * 8) = o.v;
    } else {
        if (wk == 0) {
            float* C = (float*)Cv;
            #pragma unroll
            for (int mi = 0; mi < 2; ++mi) {
                #pragma unroll
                for (int nj = 0; nj < 2; ++nj) {
                    f32x4 o = *(const f32x4*)&red[((wmn * 2 + mi) * 2 + nj) * 256 + lane * 4];
                    const int col = n0 + wn * 32 + nj * 16 + l15;
                    const float bv = bias[col];
                    #pragma unroll
                    for (int r = 0; r < 4; ++r) {
                        const int row = m0 + wm * 32 + mi * 16 + lq * 4 + r;
                        C[(size_t)row * EN + col] = acc[mi][nj][r] + o[r] + bv;
                    }
                }
            }
        }
    }
}

extern "C" void kernel_launch(void* const* d_in, const int* in_sizes, int n_in,
                              void* d_out, int out_size, void* d_ws, size_t ws_size,
                              hipStream_t stream)
{
    // inputs: x, wq, wk, wv, wc, bc, rx_params (wq/wk dead: S==1)
    const float* x  = (const float*)d_in[0];
    const float* wv = (const float*)d_in[3];
    const float* wc = (const float*)d_in[4];
    const float* bc = (const float*)d_in[5];
    const float* rx = (const float*)d_in[6];
    float* out = (float*)d_out;

    const size_t XE = (size_t)BB * EN;   // 2M elems
    const size_t WE = (size_t)EN * EN;   // 1M elems

    // ws (12 MB): [xb 4MB | wvb 2MB | wcb 2MB | V 4MB]
    __hip_bfloat16* xb  = (__hip_bfloat16*)d_ws;
    __hip_bfloat16* wvb = xb + XE;
    __hip_bfloat16* wcb = wvb + WE;
    __hip_bfloat16* V   = wcb + WE;

    dim3 grid(BB / 64, EN / 64);         // 32 x 16 = 512 blocks
    cvt3_kernel<<<(int)((XE / 8 + 2 * (WE / 8)) / 256), 256, 0, stream>>>(
        x, wv, wc, xb, wvb, wcb);
    gemm_kernel<0><<<grid, 512, 0, stream>>>(xb, wvb, nullptr, rx, V);
    gemm_kernel<1><<<grid, 512, 0, stream>>>(V, wcb, bc, nullptr, out);
}